// Round 1
// baseline (14405.769 us; speedup 1.0000x reference)
//
#include <hip/hip_runtime.h>
#include <hip/hip_fp16.h>
#include <hip/hip_bf16.h>

// ---------------- problem constants ----------------
// S=2048 words, LC=12 chars/word, E=256, H=256, EC=64, HC=128, V=50000, VC=128, T=50
// char gates: 4*HC = 512 ; word gates: 4*H = 1024 ; word input = E+HC = 384

#define DEVI __device__ __forceinline__

DEVI float sigmoidf_(float x) { return 1.f / (1.f + __expf(-x)); }
DEVI float tanhf_(float x)    { return 1.f - 2.f / (__expf(2.f * x) + 1.f); }

DEVI __half2 i2h2(int x) { union { int i; __half2 h; } u; u.i = x; return u.h; }
DEVI int h22i(__half2 h) { union { int i; __half2 h; } u; u.h = h; return u.i; }

// ---------------- workspace layout (bytes) ----------------
// CG     : float[128][512]      @ 0        (262144)
// SEQLEN : int                  @ 262144
// SEQ    : int[24576]           @ 262208   (98304)
// CH16   : half[2048][128]      @ 360512   (524288)
// XGW    : float[2048][1024]    @ 884800   (8388608)
// HWOUT  : float[2048][256]     @ 9273408  (2097152)  -> total ~11.4 MB

// ================= kernel 1: compact char sequence =================
// seq[t] = cid (bits 0..6) | LAST flag (bit 8); length = sum of clamped word_lens
__global__ __launch_bounds__(256) void k_seq(const int* __restrict__ word_chars,
                                             const int* __restrict__ word_lens,
                                             int* __restrict__ SEQ,
                                             int* __restrict__ SEQLEN) {
    __shared__ int psum[256];
    const int t = threadIdx.x;
    int l8[8];
    int local = 0;
#pragma unroll
    for (int i = 0; i < 8; ++i) {
        int L = word_lens[t * 8 + i];
        L = (L < 1) ? 1 : ((L > 12) ? 12 : L);
        l8[i] = L;
        local += L;
    }
    psum[t] = local;
    __syncthreads();
    if (t == 0) {
        int acc = 0;
        for (int i = 0; i < 256; ++i) { int v = psum[i]; psum[i] = acc; acc += v; }
        SEQLEN[0] = acc;
    }
    __syncthreads();
    int off = psum[t];
    for (int i = 0; i < 8; ++i) {
        const int s = t * 8 + i;
        const int L = l8[i];
        for (int l = 0; l < L; ++l) {
            const int cid = word_chars[s * 12 + l] & 127;
            SEQ[off + l] = cid | ((l == L - 1) ? 256 : 0);
        }
        off += L;
    }
}

// ================= kernel 2: char input-gate table =================
// CG[cid][g] = char_emb[cid] . Wih_c[g] + bih_c[g] + bhh_c[g]
__global__ __launch_bounds__(256) void k_cgates(const float* __restrict__ char_emb,
                                                const float* __restrict__ Wih_c,
                                                const float* __restrict__ bih_c,
                                                const float* __restrict__ bhh_c,
                                                float* __restrict__ CG) {
    __shared__ float x[64];
    const int cid = blockIdx.x;
    if (threadIdx.x < 64) x[threadIdx.x] = char_emb[cid * 64 + threadIdx.x];
    __syncthreads();
    for (int g = threadIdx.x; g < 512; g += 256) {
        const float* w = Wih_c + g * 64;
        float acc = 0.f;
#pragma unroll
        for (int k = 0; k < 64; k += 4) {
            const float4 wv = *(const float4*)(w + k);
            acc += wv.x * x[k] + wv.y * x[k + 1] + wv.z * x[k + 2] + wv.w * x[k + 3];
        }
        CG[cid * 512 + g] = acc + bih_c[g] + bhh_c[g];
    }
}

// ================= kernel 3: word input gates (embedding part) =================
// XGW[s][g] = word_emb[sentence[s]] . Wih_w[g][0:256] + bih_w[g] + bhh_w[g]
__global__ __launch_bounds__(256) void k_xgw(const int* __restrict__ sentence,
                                             const float* __restrict__ word_emb,
                                             const float* __restrict__ Wih_w,
                                             const float* __restrict__ bih_w,
                                             const float* __restrict__ bhh_w,
                                             float* __restrict__ XGW) {
    __shared__ float x[256];
    const int s = blockIdx.x;
    const int wid = sentence[s];
    x[threadIdx.x] = word_emb[(size_t)wid * 256 + threadIdx.x];
    __syncthreads();
    for (int g = threadIdx.x; g < 1024; g += 256) {
        const float* w = Wih_w + g * 384;
        float acc = bih_w[g] + bhh_w[g];
#pragma unroll 8
        for (int k = 0; k < 256; k += 4) {
            const float4 wv = *(const float4*)(w + k);
            acc += wv.x * x[k] + wv.y * x[k + 1] + wv.z * x[k + 2] + wv.w * x[k + 3];
        }
        XGW[s * 1024 + g] = acc;
    }
}

// ================= kernel 5: word input gates (char-hidden part) =================
// XGW[s][g] += ch_h[s] . Wih_w[g][256:384]
__global__ __launch_bounds__(256) void k_xgw_ch(const float* __restrict__ Wih_w,
                                                const __half* __restrict__ CH16,
                                                float* __restrict__ XGW) {
    __shared__ float xc[128];
    const int s = blockIdx.x;
    if (threadIdx.x < 128) xc[threadIdx.x] = __half2float(CH16[s * 128 + threadIdx.x]);
    __syncthreads();
    for (int g = threadIdx.x; g < 1024; g += 256) {
        const float* w = Wih_w + g * 384 + 256;
        float acc = 0.f;
#pragma unroll 8
        for (int k = 0; k < 128; k += 4) {
            const float4 wv = *(const float4*)(w + k);
            acc += wv.x * xc[k] + wv.y * xc[k + 1] + wv.z * xc[k + 2] + wv.w * xc[k + 3];
        }
        XGW[s * 1024 + g] += acc;
    }
}

// ================= kernel 4: char LSTM scan (1 workgroup, 256 threads) =================
// thread t owns gates g0=t (i/f) and g1=t+256 (g/o). Whh rows held as half2 in VGPRs.
// h (128 x f16) broadcast through LDS; c held in threads t<128.
__global__ __launch_bounds__(256) void k_char(const int* __restrict__ SEQ,
                                              const int* __restrict__ SEQLEN,
                                              const float* __restrict__ CG,
                                              const float* __restrict__ Whh_c,
                                              __half* __restrict__ CH16) {
    __shared__ __half2 hbuf[64];    // 128 h values as f16
    __shared__ float act[512];
    const int t = threadIdx.x;
    const int g0 = t, g1 = t + 256;

    __half2 w0[64], w1[64];
    {
        const float* r0 = Whh_c + g0 * 128;
        const float* r1 = Whh_c + g1 * 128;
#pragma unroll
        for (int j = 0; j < 64; ++j) {
            w0[j] = __floats2half2_rn(r0[2 * j], r0[2 * j + 1]);
            w1[j] = __floats2half2_rn(r1[2 * j], r1[2 * j + 1]);
        }
    }
    if (t < 64) hbuf[t] = __float2half2_rn(0.f);
    float c = 0.f;
    int wcount = 0;
    const int NT = SEQLEN[0];
    __syncthreads();

    int e_cur = SEQ[0];
    float xg0 = CG[(e_cur & 127) * 512 + g0];
    float xg1 = CG[(e_cur & 127) * 512 + g1];

    for (int tt = 0; tt < NT; ++tt) {
        int e_nx = 0;
        float xg0n = 0.f, xg1n = 0.f;
        if (tt + 1 < NT) {                       // uniform branch; prefetch next step
            e_nx = SEQ[tt + 1];
            const int r = (e_nx & 127) * 512;
            xg0n = CG[r + g0];
            xg1n = CG[r + g1];
        }

        const __half2 z = __float2half2_rn(0.f);
        __half2 a0 = z, a1 = z, a2 = z, a3 = z;
        __half2 b0 = z, b1 = z, b2 = z, b3 = z;
        const int4* hp = (const int4*)hbuf;
#pragma unroll
        for (int i = 0; i < 16; ++i) {
            const int4 v = hp[i];
            const __half2 h0 = i2h2(v.x), h1 = i2h2(v.y), h2 = i2h2(v.z), h3 = i2h2(v.w);
            a0 = __hfma2(w0[4 * i + 0], h0, a0);
            a1 = __hfma2(w0[4 * i + 1], h1, a1);
            a2 = __hfma2(w0[4 * i + 2], h2, a2);
            a3 = __hfma2(w0[4 * i + 3], h3, a3);
            b0 = __hfma2(w1[4 * i + 0], h0, b0);
            b1 = __hfma2(w1[4 * i + 1], h1, b1);
            b2 = __hfma2(w1[4 * i + 2], h2, b2);
            b3 = __hfma2(w1[4 * i + 3], h3, b3);
        }
        const __half2 sa = __hadd2(__hadd2(a0, a1), __hadd2(a2, a3));
        const __half2 sb = __hadd2(__hadd2(b0, b1), __hadd2(b2, b3));
        const float gate0 = xg0 + __low2float(sa) + __high2float(sa);
        const float gate1 = xg1 + __low2float(sb) + __high2float(sb);

        act[g0] = sigmoidf_(gate0);                                 // i or f
        act[g1] = (t < 128) ? tanhf_(gate1) : sigmoidf_(gate1);      // g or o
        __syncthreads();

        if (t < 128) {
            const float iv = act[t], fv = act[t + 128], gv = act[t + 256], ov = act[t + 384];
            c = fv * c + iv * gv;
            const float h = ov * tanhf_(c);
            const __half hh = __float2half(h);
            ((__half*)hbuf)[t] = hh;
            if (e_cur & 256) CH16[wcount * 128 + t] = hh;            // emit word's final h
        }
        wcount += (e_cur >> 8) & 1;
        e_cur = e_nx; xg0 = xg0n; xg1 = xg1n;
        __syncthreads();
    }
}

// ================= kernel 6: word LSTM scan (1 workgroup, 512 threads) =================
// thread t owns gates g0=t (i/f) and g1=t+512 (g/o).
// Whh_w row: k=0..207 (104 half2) in VGPRs, k=208..255 (24 half2 = 6 int4-chunks) in LDS.
// LDS row stride 13*int4 = 208B (16B aligned, start bank rotates 8 ways -> balanced).
__global__ __launch_bounds__(512) void k_word(const float* __restrict__ XGW,
                                              const float* __restrict__ Whh_w,
                                              float* __restrict__ HWOUT) {
    __shared__ int4 wlds[512 * 13];   // 104 KB
    __shared__ __half2 hbuf[128];     // 256 h values as f16
    __shared__ float act[1024];
    const int t = threadIdx.x;
    const int g0 = t, g1 = t + 512;

    __half2 wa[104], wb[104];
    {
        const float* r0 = Whh_w + g0 * 256;
        const float* r1 = Whh_w + g1 * 256;
#pragma unroll
        for (int j = 0; j < 104; ++j) {
            wa[j] = __floats2half2_rn(r0[2 * j], r0[2 * j + 1]);
            wb[j] = __floats2half2_rn(r1[2 * j], r1[2 * j + 1]);
        }
#pragma unroll
        for (int cc = 0; cc < 6; ++cc) {
            const int jb = 104 + 4 * cc;
            int4 p0, p1;
            p0.x = h22i(__floats2half2_rn(r0[2 * jb + 0], r0[2 * jb + 1]));
            p0.y = h22i(__floats2half2_rn(r0[2 * jb + 2], r0[2 * jb + 3]));
            p0.z = h22i(__floats2half2_rn(r0[2 * jb + 4], r0[2 * jb + 5]));
            p0.w = h22i(__floats2half2_rn(r0[2 * jb + 6], r0[2 * jb + 7]));
            p1.x = h22i(__floats2half2_rn(r1[2 * jb + 0], r1[2 * jb + 1]));
            p1.y = h22i(__floats2half2_rn(r1[2 * jb + 2], r1[2 * jb + 3]));
            p1.z = h22i(__floats2half2_rn(r1[2 * jb + 4], r1[2 * jb + 5]));
            p1.w = h22i(__floats2half2_rn(r1[2 * jb + 6], r1[2 * jb + 7]));
            wlds[t * 13 + cc] = p0;
            wlds[t * 13 + 6 + cc] = p1;
        }
    }
    if (t < 256) ((__half*)hbuf)[t] = __float2half(0.f);
    float c = 0.f;
    __syncthreads();

    float xg0 = XGW[g0];
    float xg1 = XGW[g1];

    for (int s = 0; s < 2048; ++s) {
        float xg0n = 0.f, xg1n = 0.f;
        if (s + 1 < 2048) {                       // prefetch next row
            const float* row = XGW + (s + 1) * 1024;
            xg0n = row[g0];
            xg1n = row[g1];
        }

        const __half2 z = __float2half2_rn(0.f);
        __half2 a0 = z, a1 = z, a2 = z, a3 = z;
        __half2 b0 = z, b1 = z, b2 = z, b3 = z;
        const int4* hp = (const int4*)hbuf;
#pragma unroll
        for (int i = 0; i < 26; ++i) {            // k = 0..207 from VGPRs
            const int4 v = hp[i];
            a0 = __hfma2(wa[4 * i + 0], i2h2(v.x), a0);
            a1 = __hfma2(wa[4 * i + 1], i2h2(v.y), a1);
            a2 = __hfma2(wa[4 * i + 2], i2h2(v.z), a2);
            a3 = __hfma2(wa[4 * i + 3], i2h2(v.w), a3);
            b0 = __hfma2(wb[4 * i + 0], i2h2(v.x), b0);
            b1 = __hfma2(wb[4 * i + 1], i2h2(v.y), b1);
            b2 = __hfma2(wb[4 * i + 2], i2h2(v.z), b2);
            b3 = __hfma2(wb[4 * i + 3], i2h2(v.w), b3);
        }
#pragma unroll
        for (int cc = 0; cc < 6; ++cc) {          // k = 208..255 from LDS
            const int4 v = hp[26 + cc];
            const int4 u0 = wlds[t * 13 + cc];
            const int4 u1 = wlds[t * 13 + 6 + cc];
            a0 = __hfma2(i2h2(u0.x), i2h2(v.x), a0);
            a1 = __hfma2(i2h2(u0.y), i2h2(v.y), a1);
            a2 = __hfma2(i2h2(u0.z), i2h2(v.z), a2);
            a3 = __hfma2(i2h2(u0.w), i2h2(v.w), a3);
            b0 = __hfma2(i2h2(u1.x), i2h2(v.x), b0);
            b1 = __hfma2(i2h2(u1.y), i2h2(v.y), b1);
            b2 = __hfma2(i2h2(u1.z), i2h2(v.z), b2);
            b3 = __hfma2(i2h2(u1.w), i2h2(v.w), b3);
        }
        const __half2 sa = __hadd2(__hadd2(a0, a1), __hadd2(a2, a3));
        const __half2 sb = __hadd2(__hadd2(b0, b1), __hadd2(b2, b3));
        const float gate0 = xg0 + __low2float(sa) + __high2float(sa);
        const float gate1 = xg1 + __low2float(sb) + __high2float(sb);

        act[g0] = sigmoidf_(gate0);                                  // i or f
        act[g1] = (t < 256) ? tanhf_(gate1) : sigmoidf_(gate1);       // g or o
        __syncthreads();

        if (t < 256) {
            const float iv = act[t], fv = act[t + 256], gv = act[t + 512], ov = act[t + 768];
            c = fv * c + iv * gv;
            const float h = ov * tanhf_(c);
            HWOUT[s * 256 + t] = h;
            ((__half*)hbuf)[t] = __float2half(h);
        }
        xg0 = xg0n; xg1 = xg1n;
        __syncthreads();
    }
}

// ================= kernel 7: tag projection + log_softmax =================
__global__ __launch_bounds__(64) void k_tag(const float* __restrict__ HWOUT,
                                            const float* __restrict__ W_tag,
                                            const float* __restrict__ b_tag,
                                            float* __restrict__ out) {
    const int s = blockIdx.x, t = threadIdx.x;
    float logit = -1e30f;
    if (t < 50) {
        const float* w = W_tag + t * 256;
        const float* h = HWOUT + s * 256;
        float acc = b_tag[t];
#pragma unroll 8
        for (int k = 0; k < 256; k += 4) {
            const float4 wv = *(const float4*)(w + k);
            const float4 hv = *(const float4*)(h + k);
            acc += wv.x * hv.x + wv.y * hv.y + wv.z * hv.z + wv.w * hv.w;
        }
        logit = acc;
    }
    float m = logit;
#pragma unroll
    for (int off = 32; off > 0; off >>= 1) m = fmaxf(m, __shfl_xor(m, off));
    float ex = (t < 50) ? __expf(logit - m) : 0.f;
    float ssum = ex;
#pragma unroll
    for (int off = 32; off > 0; off >>= 1) ssum += __shfl_xor(ssum, off);
    const float lse = __logf(ssum);
    if (t < 50) out[s * 50 + t] = (logit - m) - lse;
}

// ================= launch =================
extern "C" void kernel_launch(void* const* d_in, const int* in_sizes, int n_in,
                              void* d_out, int out_size, void* d_ws, size_t ws_size,
                              hipStream_t stream) {
    const int*   sentence   = (const int*)d_in[0];
    const int*   word_chars = (const int*)d_in[1];
    const int*   word_lens  = (const int*)d_in[2];
    const float* word_emb   = (const float*)d_in[5];
    const float* char_emb   = (const float*)d_in[6];
    const float* Wih_c      = (const float*)d_in[7];
    const float* Whh_c      = (const float*)d_in[8];
    const float* bih_c      = (const float*)d_in[9];
    const float* bhh_c      = (const float*)d_in[10];
    const float* Wih_w      = (const float*)d_in[11];
    const float* Whh_w      = (const float*)d_in[12];
    const float* bih_w      = (const float*)d_in[13];
    const float* bhh_w      = (const float*)d_in[14];
    const float* W_tag      = (const float*)d_in[15];
    const float* b_tag      = (const float*)d_in[16];
    float* out = (float*)d_out;

    char* ws = (char*)d_ws;
    float*  CG     = (float*)(ws + 0);
    int*    SEQLEN = (int*)(ws + 262144);
    int*    SEQ    = (int*)(ws + 262208);
    __half* CH16   = (__half*)(ws + 360512);
    float*  XGW    = (float*)(ws + 884800);
    float*  HWOUT  = (float*)(ws + 9273408);

    k_seq   <<<1,    256, 0, stream>>>(word_chars, word_lens, SEQ, SEQLEN);
    k_cgates<<<128,  256, 0, stream>>>(char_emb, Wih_c, bih_c, bhh_c, CG);
    k_xgw   <<<2048, 256, 0, stream>>>(sentence, word_emb, Wih_w, bih_w, bhh_w, XGW);
    k_char  <<<1,    256, 0, stream>>>(SEQ, SEQLEN, CG, Whh_c, CH16);
    k_xgw_ch<<<2048, 256, 0, stream>>>(Wih_w, CH16, XGW);
    k_word  <<<1,    512, 0, stream>>>(XGW, Whh_w, HWOUT);
    k_tag   <<<2048, 64,  0, stream>>>(HWOUT, W_tag, b_tag, out);
}